// Round 14
// baseline (1218.646 us; speedup 1.0000x reference)
//
#include <hip/hip_runtime.h>

#define FIN 512
#define FHID 16
#define FOUT 40
#define NBH 256          // histogram blocks (1 per CU)
#define HWORDS_MAX 32768 // 128KB LDS byte-histogram -> n <= 131072

typedef __attribute__((ext_vector_type(8))) short bf16x8;
typedef __attribute__((ext_vector_type(4))) float f32x4;

// 4x16-bit biased fixed-point fields per u64 atomic (validated rounds 10/12/13).
#define ENC_S 32.0f
#define ENC_SI 0.03125f
#define ENC_B 8.0f

__device__ __forceinline__ unsigned long long enc4(float a, float b, float c, float d) {
    unsigned r0 = (unsigned)fmaf(a, ENC_S, 256.5f);
    unsigned r1 = (unsigned)fmaf(b, ENC_S, 256.5f);
    unsigned r2 = (unsigned)fmaf(c, ENC_S, 256.5f);
    unsigned r3 = (unsigned)fmaf(d, ENC_S, 256.5f);
    return (unsigned long long)r0 | ((unsigned long long)r1 << 16) |
           ((unsigned long long)r2 << 32) | ((unsigned long long)r3 << 48);
}

__device__ __forceinline__ unsigned bfpack2(float a, float b) {
    unsigned ua = __float_as_uint(a);
    unsigned ub = __float_as_uint(b);
    unsigned ra = (ua + 0x7fffu + ((ua >> 16) & 1u)) >> 16;
    unsigned rb = (ub + 0x7fffu + ((ub >> 16) & 1u)) & 0xffff0000u;
    return ra | rb;
}

__device__ __forceinline__ short bf1(float a) {
    unsigned ua = __float_as_uint(a);
    return (short)((ua + 0x7fffu + ((ua >> 16) & 1u)) >> 16);
}

// ---------------- degree via per-CU LDS byte-histogram (validated round 13) ---------

__global__ __launch_bounds__(256) void k_hist(const int* __restrict__ dst,
                                              unsigned* __restrict__ histg,
                                              int E, int words) {
    __shared__ unsigned hist[HWORDS_MAX];  // 128 KiB
    int t = threadIdx.x;
    for (int i = t; i < words; i += 256) hist[i] = 0;
    __syncthreads();

    int chunk = (E + NBH - 1) / NBH;
    int beg = blockIdx.x * chunk;
    int end = beg + chunk; if (end > E) end = E;
    for (int i = beg + t; i < end; i += 256) {
        int d = dst[i];
        atomicAdd(&hist[d >> 2], 1u << ((d & 3) * 8));
    }
    __syncthreads();

    unsigned* outp = histg + (size_t)blockIdx.x * words;
    for (int i = t; i < words; i += 256) outp[i] = hist[i];
}

__global__ __launch_bounds__(256) void k_merge(const unsigned* __restrict__ histg,
                                               int words, int* __restrict__ cnt,
                                               float* __restrict__ dinv, int n) {
    int wd = blockIdx.x * 256 + threadIdx.x;
    if (wd >= words) return;
    unsigned s0 = 0, s1 = 0, s2 = 0, s3 = 0;
    const unsigned* p = histg + wd;
#pragma unroll 8
    for (int b = 0; b < NBH; ++b) {
        unsigned v = p[(size_t)b * words];
        s0 += v & 0xFFu;
        s1 += (v >> 8) & 0xFFu;
        s2 += (v >> 16) & 0xFFu;
        s3 += (v >> 24) & 0xFFu;
    }
    int nd = wd * 4;
    unsigned c[4] = {s0, s1, s2, s3};
#pragma unroll
    for (int j = 0; j < 4; ++j) {
        if (nd + j < n) {
            cnt[nd + j] = (int)c[j];
            dinv[nd + j] = rsqrtf((float)(c[j] + 1));
        }
    }
}

// ---------------- layer 1 GEMM via MFMA: genc = agg = enc4((x@W1)*dinv) -------------

__global__ __launch_bounds__(256, 2) void k_gemm1(const float* __restrict__ x,
                                                  const float* __restrict__ W1,
                                                  const float* __restrict__ dinv,
                                                  unsigned long long* __restrict__ genc,
                                                  unsigned long long* __restrict__ agg,
                                                  int n, int npanels) {
    __shared__ short xs[64 * 512];  // 64 KiB, XOR-swizzled rows

    int t = threadIdx.x;
    int lane = t & 63;
    int wv = t >> 6;
    int kg = lane >> 4;
    int lcol = lane & 15;

    bf16x8 wf[16];
#pragma unroll
    for (int s = 0; s < 16; ++s) {
#pragma unroll
        for (int j = 0; j < 8; ++j)
            wf[s][j] = bf1(W1[(s * 32 + kg * 8 + j) * FHID + lcol]);
    }

    const size_t maxoff = (size_t)n * (FIN * 4) - 16;

    for (int pb = blockIdx.x; pb < npanels; pb += gridDim.x) {
        __syncthreads();

        size_t panelbyte = (size_t)pb * 131072;
#pragma unroll 1
        for (int b = 0; b < 4; ++b) {
            float4 v[8];
#pragma unroll
            for (int i = 0; i < 8; ++i) {
                size_t off = panelbyte + (size_t)(b * 8 + i) * 4096 + (size_t)t * 16;
                if (off > maxoff) off = maxoff;
                v[i] = *reinterpret_cast<const float4*>((const char*)x + off);
            }
#pragma unroll
            for (int i = 0; i < 8; ++i) {
                int elem = (b * 8 + i) * 1024 + t * 4;
                int row = elem >> 9;
                int kc = elem & 511;
                int kcs = kc ^ ((row & 7) << 3);
                uint2 w2;
                w2.x = bfpack2(v[i].x, v[i].y);
                w2.y = bfpack2(v[i].z, v[i].w);
                *reinterpret_cast<uint2*>(&xs[row * 512 + kcs]) = w2;
            }
        }
        __syncthreads();

        int lrow = wv * 16 + lcol;
        const short* ap = &xs[lrow * 512];
        f32x4 acc = {0.0f, 0.0f, 0.0f, 0.0f};
#pragma unroll
        for (int s = 0; s < 16; ++s) {
            int kc = s * 32 + kg * 8;
            bf16x8 a = *reinterpret_cast<const bf16x8*>(ap + (kc ^ ((lrow & 7) << 3)));
            acc = __builtin_amdgcn_mfma_f32_16x16x32_bf16(a, wf[s], acc, 0, 0, 0);
        }

        int panelrow = pb * 64 + wv * 16;
#pragma unroll
        for (int r = 0; r < 4; ++r) {
            int grow = panelrow + kg * 4 + r;
            float dv = (grow < n) ? dinv[grow] : 0.0f;
            float val = acc[r] * dv;
            float v1 = __shfl_xor(val, 1);
            float v2 = __shfl_xor(val, 2);
            float v3 = __shfl_xor(val, 3);
            if (grow < n && (lcol & 3) == 0) {
                unsigned long long e4 = enc4(val, v1, v2, v3);
                genc[(size_t)grow * 4 + (lcol >> 2)] = e4;
                agg[(size_t)grow * 4 + (lcol >> 2)] = e4;  // self-loop init
            }
        }
    }
}

// ---------------- edge scatter: 1 thread/edge, pre-encoded row, 4 u64 atomics -------
// Minimal per-edge path: 2 idx loads + 32B gather + 4 fire-and-forget atomics.

__global__ __launch_bounds__(256) void k_scat1(const int* __restrict__ src,
                                               const int* __restrict__ dst,
                                               const unsigned long long* __restrict__ genc,
                                               unsigned long long* __restrict__ agg,
                                               int E) {
    int e = blockIdx.x * 256 + threadIdx.x;
    if (e >= E) return;
    int s = src[e];
    int d = dst[e];
    const ulonglong2* gp = reinterpret_cast<const ulonglong2*>(genc + (size_t)s * 4);
    ulonglong2 a = gp[0];
    ulonglong2 b = gp[1];
    unsigned long long* ap = agg + (size_t)d * 4;
    atomicAdd(&ap[0], a.x);
    atomicAdd(&ap[1], a.y);
    atomicAdd(&ap[2], b.x);
    atomicAdd(&ap[3], b.y);
}

// ---------------- finish layer 1: decode; p = relu(s*dinv + b1)*dinv; re-encode -----

__global__ void k_finish1(const unsigned long long* __restrict__ agg,
                          const int* __restrict__ cnt,
                          const float* __restrict__ dinv,
                          const float* __restrict__ b1,
                          unsigned long long* __restrict__ penc,
                          unsigned long long* __restrict__ aggp, int n) {
    int nd = blockIdx.x * blockDim.x + threadIdx.x;
    if (nd >= n) return;
    float dv = dinv[nd];
    float cb = (float)(cnt[nd] + 1) * ENC_B;
    const unsigned long long* ar = agg + (size_t)nd * 4;
    unsigned long long* pp = penc + (size_t)nd * 4;
    unsigned long long* ap = aggp + (size_t)nd * 4;
#pragma unroll
    for (int j = 0; j < 4; ++j) {
        unsigned long long w = ar[j];
        float s0 = (float)(unsigned)(w & 0xFFFF) * ENC_SI - cb;
        float s1 = (float)(unsigned)((w >> 16) & 0xFFFF) * ENC_SI - cb;
        float s2 = (float)(unsigned)((w >> 32) & 0xFFFF) * ENC_SI - cb;
        float s3 = (float)(unsigned)((w >> 48) & 0xFFFF) * ENC_SI - cb;
        float r0 = fmaxf(fmaf(s0, dv, b1[4 * j + 0]), 0.0f) * dv;
        float r1 = fmaxf(fmaf(s1, dv, b1[4 * j + 1]), 0.0f) * dv;
        float r2 = fmaxf(fmaf(s2, dv, b1[4 * j + 2]), 0.0f) * dv;
        float r3 = fmaxf(fmaf(s3, dv, b1[4 * j + 3]), 0.0f) * dv;
        unsigned long long e4 = enc4(r0, r1, r2, r3);
        pp[j] = e4;
        ap[j] = e4;  // self-loop init for layer 2
    }
}

// ---------------- finish layer 2: decode; out = log_softmax((s*dinv) @ W2 + b2) -----

__global__ __launch_bounds__(256) void k_finish2(const unsigned long long* __restrict__ aggp,
                                                 const int* __restrict__ cnt,
                                                 const float* __restrict__ dinv,
                                                 const float* __restrict__ W2,
                                                 const float* __restrict__ b2,
                                                 float* __restrict__ out, int n) {
    __shared__ float Wl[FHID * FOUT];
    __shared__ float bl[FOUT];
    for (int i = threadIdx.x; i < FHID * FOUT; i += 256) Wl[i] = W2[i];
    if (threadIdx.x < FOUT) bl[threadIdx.x] = b2[threadIdx.x];
    __syncthreads();

    int nd = blockIdx.x * 256 + threadIdx.x;
    if (nd >= n) return;

    float dv = dinv[nd];
    float cb = (float)(cnt[nd] + 1) * ENC_B;
    float q[FHID];
    const unsigned long long* ap = aggp + (size_t)nd * 4;
#pragma unroll
    for (int j = 0; j < 4; ++j) {
        unsigned long long w = ap[j];
        q[4 * j + 0] = ((float)(unsigned)(w & 0xFFFF) * ENC_SI - cb) * dv;
        q[4 * j + 1] = ((float)(unsigned)((w >> 16) & 0xFFFF) * ENC_SI - cb) * dv;
        q[4 * j + 2] = ((float)(unsigned)((w >> 32) & 0xFFFF) * ENC_SI - cb) * dv;
        q[4 * j + 3] = ((float)(unsigned)((w >> 48) & 0xFFFF) * ENC_SI - cb) * dv;
    }

    float acc[FOUT];
#pragma unroll
    for (int o = 0; o < FOUT; ++o) acc[o] = bl[o];
#pragma unroll
    for (int k = 0; k < FHID; ++k) {
        float qs = q[k];
        const float* wrow = &Wl[k * FOUT];
#pragma unroll
        for (int o = 0; o < FOUT; ++o) acc[o] = fmaf(qs, wrow[o], acc[o]);
    }

    float m = acc[0];
#pragma unroll
    for (int o = 1; o < FOUT; ++o) m = fmaxf(m, acc[o]);
    float ssum = 0.0f;
#pragma unroll
    for (int o = 0; o < FOUT; ++o) ssum += expf(acc[o] - m);
    float lse = m + logf(ssum);

    float4* op = reinterpret_cast<float4*>(out + (size_t)nd * FOUT);
#pragma unroll
    for (int tt = 0; tt < FOUT / 4; ++tt) {
        float4 v;
        v.x = acc[4 * tt + 0] - lse;
        v.y = acc[4 * tt + 1] - lse;
        v.z = acc[4 * tt + 2] - lse;
        v.w = acc[4 * tt + 3] - lse;
        op[tt] = v;
    }
}

// ---------------- launch ----------------

extern "C" void kernel_launch(void* const* d_in, const int* in_sizes, int n_in,
                              void* d_out, int out_size, void* d_ws, size_t ws_size,
                              hipStream_t stream) {
    const float* x  = (const float*)d_in[0];
    const int*   ei = (const int*)d_in[1];
    const float* W1 = (const float*)d_in[2];
    const float* b1 = (const float*)d_in[3];
    const float* W2 = (const float*)d_in[4];
    const float* b2 = (const float*)d_in[5];

    const int fh = in_sizes[3];              // 16
    const int fi = in_sizes[2] / fh;         // 512
    const int n  = in_sizes[0] / fi;         // 100000
    const int E  = in_sizes[1] / 2;          // 3200000
    (void)n_in; (void)out_size; (void)ws_size;

    const int* src = ei;
    const int* dst = ei + E;

    const int words = (n + 3) >> 2;

    char* w = (char*)d_ws;
    unsigned* histg = (unsigned*)w;                     w += (size_t)NBH * words * 4;
    int*   cnt  = (int*)w;                              w += (size_t)n * 4;
    float* dinv = (float*)w;                            w += (size_t)n * 4;
    unsigned long long* genc = (unsigned long long*)w;  w += (size_t)n * 4 * 8;
    unsigned long long* agg  = (unsigned long long*)w;  w += (size_t)n * 4 * 8;
    unsigned long long* penc = (unsigned long long*)w;  w += (size_t)n * 4 * 8;
    unsigned long long* aggp = (unsigned long long*)w;

    float* out = (float*)d_out;

    const int TB = 256;
    const int nb_n = (n + TB - 1) / TB;
    const int nb_e = (E + TB - 1) / TB;
    const int npanels = (n + 63) / 64;

    k_hist<<<NBH, TB, 0, stream>>>(dst, histg, E, words);
    k_merge<<<(words + TB - 1) / TB, TB, 0, stream>>>(histg, words, cnt, dinv, n);

    k_gemm1<<<512, TB, 0, stream>>>(x, W1, dinv, genc, agg, n, npanels);
    k_scat1<<<nb_e, TB, 0, stream>>>(src, dst, genc, agg, E);
    k_finish1<<<nb_n, TB, 0, stream>>>(agg, cnt, dinv, b1, penc, aggp, n);
    k_scat1<<<nb_e, TB, 0, stream>>>(src, dst, penc, aggp, E);
    k_finish2<<<nb_n, TB, 0, stream>>>(aggp, cnt, dinv, W2, b2, out, n);
}

// Round 15
// 374.980 us; speedup vs baseline: 3.2499x; 3.2499x over previous
//
#include <hip/hip_runtime.h>

#define FIN 512
#define FHID 16
#define FOUT 40
#define NBH 256          // histogram blocks (1 per CU)
#define HWORDS_MAX 32768 // 128KB LDS byte-histogram -> n <= 131072

typedef __attribute__((ext_vector_type(8))) short bf16x8;
typedef __attribute__((ext_vector_type(4))) float f32x4;

// 4x16-bit biased fixed-point fields per u64 atomic (validated rounds 10/12/13).
#define ENC_S 32.0f
#define ENC_SI 0.03125f
#define ENC_B 8.0f

__device__ __forceinline__ unsigned long long enc4(float a, float b, float c, float d) {
    unsigned r0 = (unsigned)fmaf(a, ENC_S, 256.5f);
    unsigned r1 = (unsigned)fmaf(b, ENC_S, 256.5f);
    unsigned r2 = (unsigned)fmaf(c, ENC_S, 256.5f);
    unsigned r3 = (unsigned)fmaf(d, ENC_S, 256.5f);
    return (unsigned long long)r0 | ((unsigned long long)r1 << 16) |
           ((unsigned long long)r2 << 32) | ((unsigned long long)r3 << 48);
}

__device__ __forceinline__ unsigned bfpack2(float a, float b) {
    unsigned ua = __float_as_uint(a);
    unsigned ub = __float_as_uint(b);
    unsigned ra = (ua + 0x7fffu + ((ua >> 16) & 1u)) >> 16;
    unsigned rb = (ub + 0x7fffu + ((ub >> 16) & 1u)) & 0xffff0000u;
    return ra | rb;
}

__device__ __forceinline__ short bf1(float a) {
    unsigned ua = __float_as_uint(a);
    return (short)((ua + 0x7fffu + ((ua >> 16) & 1u)) >> 16);
}

// ---------------- degree via per-CU LDS byte-histogram (validated round 13) ---------

__global__ __launch_bounds__(256) void k_hist(const int* __restrict__ dst,
                                              unsigned* __restrict__ histg,
                                              int E, int words) {
    __shared__ unsigned hist[HWORDS_MAX];  // 128 KiB
    int t = threadIdx.x;
    for (int i = t; i < words; i += 256) hist[i] = 0;
    __syncthreads();

    int chunk = (E + NBH - 1) / NBH;
    int beg = blockIdx.x * chunk;
    int end = beg + chunk; if (end > E) end = E;
    for (int i = beg + t; i < end; i += 256) {
        int d = dst[i];
        atomicAdd(&hist[d >> 2], 1u << ((d & 3) * 8));
    }
    __syncthreads();

    unsigned* outp = histg + (size_t)blockIdx.x * words;
    for (int i = t; i < words; i += 256) outp[i] = hist[i];
}

__global__ __launch_bounds__(256) void k_merge(const unsigned* __restrict__ histg,
                                               int words, int* __restrict__ cnt,
                                               float* __restrict__ dinv, int n) {
    int wd = blockIdx.x * 256 + threadIdx.x;
    if (wd >= words) return;
    unsigned s0 = 0, s1 = 0, s2 = 0, s3 = 0;
    const unsigned* p = histg + wd;
#pragma unroll 8
    for (int b = 0; b < NBH; ++b) {
        unsigned v = p[(size_t)b * words];
        s0 += v & 0xFFu;
        s1 += (v >> 8) & 0xFFu;
        s2 += (v >> 16) & 0xFFu;
        s3 += (v >> 24) & 0xFFu;
    }
    int nd = wd * 4;
    unsigned c[4] = {s0, s1, s2, s3};
#pragma unroll
    for (int j = 0; j < 4; ++j) {
        if (nd + j < n) {
            cnt[nd + j] = (int)c[j];
            dinv[nd + j] = rsqrtf((float)(c[j] + 1));
        }
    }
}

// ---------------- layer 1 GEMM via MFMA: genc = agg = enc4((x@W1)*dinv) -------------

__global__ __launch_bounds__(256, 2) void k_gemm1(const float* __restrict__ x,
                                                  const float* __restrict__ W1,
                                                  const float* __restrict__ dinv,
                                                  unsigned long long* __restrict__ genc,
                                                  unsigned long long* __restrict__ agg,
                                                  int n, int npanels) {
    __shared__ short xs[64 * 512];  // 64 KiB, XOR-swizzled rows

    int t = threadIdx.x;
    int lane = t & 63;
    int wv = t >> 6;
    int kg = lane >> 4;
    int lcol = lane & 15;

    bf16x8 wf[16];
#pragma unroll
    for (int s = 0; s < 16; ++s) {
#pragma unroll
        for (int j = 0; j < 8; ++j)
            wf[s][j] = bf1(W1[(s * 32 + kg * 8 + j) * FHID + lcol]);
    }

    const size_t maxoff = (size_t)n * (FIN * 4) - 16;

    for (int pb = blockIdx.x; pb < npanels; pb += gridDim.x) {
        __syncthreads();

        size_t panelbyte = (size_t)pb * 131072;
#pragma unroll 1
        for (int b = 0; b < 4; ++b) {
            float4 v[8];
#pragma unroll
            for (int i = 0; i < 8; ++i) {
                size_t off = panelbyte + (size_t)(b * 8 + i) * 4096 + (size_t)t * 16;
                if (off > maxoff) off = maxoff;
                v[i] = *reinterpret_cast<const float4*>((const char*)x + off);
            }
#pragma unroll
            for (int i = 0; i < 8; ++i) {
                int elem = (b * 8 + i) * 1024 + t * 4;
                int row = elem >> 9;
                int kc = elem & 511;
                int kcs = kc ^ ((row & 7) << 3);
                uint2 w2;
                w2.x = bfpack2(v[i].x, v[i].y);
                w2.y = bfpack2(v[i].z, v[i].w);
                *reinterpret_cast<uint2*>(&xs[row * 512 + kcs]) = w2;
            }
        }
        __syncthreads();

        int lrow = wv * 16 + lcol;
        const short* ap = &xs[lrow * 512];
        f32x4 acc = {0.0f, 0.0f, 0.0f, 0.0f};
#pragma unroll
        for (int s = 0; s < 16; ++s) {
            int kc = s * 32 + kg * 8;
            bf16x8 a = *reinterpret_cast<const bf16x8*>(ap + (kc ^ ((lrow & 7) << 3)));
            acc = __builtin_amdgcn_mfma_f32_16x16x32_bf16(a, wf[s], acc, 0, 0, 0);
        }

        int panelrow = pb * 64 + wv * 16;
#pragma unroll
        for (int r = 0; r < 4; ++r) {
            int grow = panelrow + kg * 4 + r;
            float dv = (grow < n) ? dinv[grow] : 0.0f;
            float val = acc[r] * dv;
            float v1 = __shfl_xor(val, 1);
            float v2 = __shfl_xor(val, 2);
            float v3 = __shfl_xor(val, 3);
            if (grow < n && (lcol & 3) == 0) {
                unsigned long long e4 = enc4(val, v1, v2, v3);
                genc[(size_t)grow * 4 + (lcol >> 2)] = e4;
                agg[(size_t)grow * 4 + (lcol >> 2)] = e4;  // self-loop init
            }
        }
    }
}

// ---------------- edge scatter: 4 lanes/edge, pre-encoded 8B gather, 1 u64 atomic ---
// Lane group j=0..3 covers one contiguous 32B agg row within ONE wave-instruction:
// TCC merges the 4 atomics into a full-sector packet (round-13 counter: WRITE==payload).
// Round-14 lesson: issuing the 4 atomics from one thread (4 separate instructions)
// write-amplifies 4x (each 8B atomic dirties a 32B sector).

__global__ __launch_bounds__(256) void k_scat4e(const int* __restrict__ src,
                                                const int* __restrict__ dst,
                                                const unsigned long long* __restrict__ genc,
                                                unsigned long long* __restrict__ agg,
                                                int E) {
    long long tid = (long long)blockIdx.x * 256 + threadIdx.x;
    int e = (int)(tid >> 2);
    int j = (int)(tid & 3);
    if (e >= E) return;
    int s = src[e];
    int d = dst[e];
    unsigned long long v = genc[(size_t)s * 4 + j];  // 8B lane-gather, 32B/edge total
    atomicAdd(&agg[(size_t)d * 4 + j], v);
}

// ---------------- finish layer 1: decode; p = relu(s*dinv + b1)*dinv; re-encode -----

__global__ void k_finish1(const unsigned long long* __restrict__ agg,
                          const int* __restrict__ cnt,
                          const float* __restrict__ dinv,
                          const float* __restrict__ b1,
                          unsigned long long* __restrict__ penc,
                          unsigned long long* __restrict__ aggp, int n) {
    int nd = blockIdx.x * blockDim.x + threadIdx.x;
    if (nd >= n) return;
    float dv = dinv[nd];
    float cb = (float)(cnt[nd] + 1) * ENC_B;
    const unsigned long long* ar = agg + (size_t)nd * 4;
    unsigned long long* pp = penc + (size_t)nd * 4;
    unsigned long long* ap = aggp + (size_t)nd * 4;
#pragma unroll
    for (int j = 0; j < 4; ++j) {
        unsigned long long w = ar[j];
        float s0 = (float)(unsigned)(w & 0xFFFF) * ENC_SI - cb;
        float s1 = (float)(unsigned)((w >> 16) & 0xFFFF) * ENC_SI - cb;
        float s2 = (float)(unsigned)((w >> 32) & 0xFFFF) * ENC_SI - cb;
        float s3 = (float)(unsigned)((w >> 48) & 0xFFFF) * ENC_SI - cb;
        float r0 = fmaxf(fmaf(s0, dv, b1[4 * j + 0]), 0.0f) * dv;
        float r1 = fmaxf(fmaf(s1, dv, b1[4 * j + 1]), 0.0f) * dv;
        float r2 = fmaxf(fmaf(s2, dv, b1[4 * j + 2]), 0.0f) * dv;
        float r3 = fmaxf(fmaf(s3, dv, b1[4 * j + 3]), 0.0f) * dv;
        unsigned long long e4 = enc4(r0, r1, r2, r3);
        pp[j] = e4;
        ap[j] = e4;  // self-loop init for layer 2
    }
}

// ---------------- finish layer 2: decode; out = log_softmax((s*dinv) @ W2 + b2) -----

__global__ __launch_bounds__(256) void k_finish2(const unsigned long long* __restrict__ aggp,
                                                 const int* __restrict__ cnt,
                                                 const float* __restrict__ dinv,
                                                 const float* __restrict__ W2,
                                                 const float* __restrict__ b2,
                                                 float* __restrict__ out, int n) {
    __shared__ float Wl[FHID * FOUT];
    __shared__ float bl[FOUT];
    for (int i = threadIdx.x; i < FHID * FOUT; i += 256) Wl[i] = W2[i];
    if (threadIdx.x < FOUT) bl[threadIdx.x] = b2[threadIdx.x];
    __syncthreads();

    int nd = blockIdx.x * 256 + threadIdx.x;
    if (nd >= n) return;

    float dv = dinv[nd];
    float cb = (float)(cnt[nd] + 1) * ENC_B;
    float q[FHID];
    const unsigned long long* ap = aggp + (size_t)nd * 4;
#pragma unroll
    for (int j = 0; j < 4; ++j) {
        unsigned long long w = ap[j];
        q[4 * j + 0] = ((float)(unsigned)(w & 0xFFFF) * ENC_SI - cb) * dv;
        q[4 * j + 1] = ((float)(unsigned)((w >> 16) & 0xFFFF) * ENC_SI - cb) * dv;
        q[4 * j + 2] = ((float)(unsigned)((w >> 32) & 0xFFFF) * ENC_SI - cb) * dv;
        q[4 * j + 3] = ((float)(unsigned)((w >> 48) & 0xFFFF) * ENC_SI - cb) * dv;
    }

    float acc[FOUT];
#pragma unroll
    for (int o = 0; o < FOUT; ++o) acc[o] = bl[o];
#pragma unroll
    for (int k = 0; k < FHID; ++k) {
        float qs = q[k];
        const float* wrow = &Wl[k * FOUT];
#pragma unroll
        for (int o = 0; o < FOUT; ++o) acc[o] = fmaf(qs, wrow[o], acc[o]);
    }

    float m = acc[0];
#pragma unroll
    for (int o = 1; o < FOUT; ++o) m = fmaxf(m, acc[o]);
    float ssum = 0.0f;
#pragma unroll
    for (int o = 0; o < FOUT; ++o) ssum += expf(acc[o] - m);
    float lse = m + logf(ssum);

    float4* op = reinterpret_cast<float4*>(out + (size_t)nd * FOUT);
#pragma unroll
    for (int tt = 0; tt < FOUT / 4; ++tt) {
        float4 v;
        v.x = acc[4 * tt + 0] - lse;
        v.y = acc[4 * tt + 1] - lse;
        v.z = acc[4 * tt + 2] - lse;
        v.w = acc[4 * tt + 3] - lse;
        op[tt] = v;
    }
}

// ---------------- launch ----------------

extern "C" void kernel_launch(void* const* d_in, const int* in_sizes, int n_in,
                              void* d_out, int out_size, void* d_ws, size_t ws_size,
                              hipStream_t stream) {
    const float* x  = (const float*)d_in[0];
    const int*   ei = (const int*)d_in[1];
    const float* W1 = (const float*)d_in[2];
    const float* b1 = (const float*)d_in[3];
    const float* W2 = (const float*)d_in[4];
    const float* b2 = (const float*)d_in[5];

    const int fh = in_sizes[3];              // 16
    const int fi = in_sizes[2] / fh;         // 512
    const int n  = in_sizes[0] / fi;         // 100000
    const int E  = in_sizes[1] / 2;          // 3200000
    (void)n_in; (void)out_size; (void)ws_size;

    const int* src = ei;
    const int* dst = ei + E;

    const int words = (n + 3) >> 2;

    char* w = (char*)d_ws;
    unsigned* histg = (unsigned*)w;                     w += (size_t)NBH * words * 4;
    int*   cnt  = (int*)w;                              w += (size_t)n * 4;
    float* dinv = (float*)w;                            w += (size_t)n * 4;
    unsigned long long* genc = (unsigned long long*)w;  w += (size_t)n * 4 * 8;
    unsigned long long* agg  = (unsigned long long*)w;  w += (size_t)n * 4 * 8;
    unsigned long long* penc = (unsigned long long*)w;  w += (size_t)n * 4 * 8;
    unsigned long long* aggp = (unsigned long long*)w;

    float* out = (float*)d_out;

    const int TB = 256;
    const int nb_n = (n + TB - 1) / TB;
    const int npanels = (n + 63) / 64;
    const int nb_s = (int)(((long long)E * 4 + TB - 1) / TB);

    k_hist<<<NBH, TB, 0, stream>>>(dst, histg, E, words);
    k_merge<<<(words + TB - 1) / TB, TB, 0, stream>>>(histg, words, cnt, dinv, n);

    k_gemm1<<<512, TB, 0, stream>>>(x, W1, dinv, genc, agg, n, npanels);
    k_scat4e<<<nb_s, TB, 0, stream>>>(src, dst, genc, agg, E);
    k_finish1<<<nb_n, TB, 0, stream>>>(agg, cnt, dinv, b1, penc, aggp, n);
    k_scat4e<<<nb_s, TB, 0, stream>>>(src, dst, penc, aggp, E);
    k_finish2<<<nb_n, TB, 0, stream>>>(aggp, cnt, dinv, W2, b2, out, n);
}

// Round 16
// 215.526 us; speedup vs baseline: 5.6543x; 1.7398x over previous
//
#include <hip/hip_runtime.h>

#define FIN 512
#define FHID 16
#define FOUT 40
#define NBH 256           // hist/fill blocks (edge chunking)
#define HWORDS_MAX 32768  // LDS byte-hist words -> n <= 131072
#define BSH 9             // bucket = node >> 9 (512 nodes/bucket)
#define NBKT_MAX 256

typedef __attribute__((ext_vector_type(8))) short bf16x8;
typedef __attribute__((ext_vector_type(4))) float f32x4;

// 4x16-bit biased fixed-point fields per u64 (validated r10/12/13/15).
// Integer sums are exact & commutative -> any accumulation order is bit-deterministic.
#define ENC_S 32.0f
#define ENC_SI 0.03125f
#define ENC_B 8.0f

__device__ __forceinline__ unsigned long long enc4(float a, float b, float c, float d) {
    unsigned r0 = (unsigned)fmaf(a, ENC_S, 256.5f);
    unsigned r1 = (unsigned)fmaf(b, ENC_S, 256.5f);
    unsigned r2 = (unsigned)fmaf(c, ENC_S, 256.5f);
    unsigned r3 = (unsigned)fmaf(d, ENC_S, 256.5f);
    return (unsigned long long)r0 | ((unsigned long long)r1 << 16) |
           ((unsigned long long)r2 << 32) | ((unsigned long long)r3 << 48);
}

__device__ __forceinline__ unsigned bfpack2(float a, float b) {
    unsigned ua = __float_as_uint(a);
    unsigned ub = __float_as_uint(b);
    unsigned ra = (ua + 0x7fffu + ((ua >> 16) & 1u)) >> 16;
    unsigned rb = (ub + 0x7fffu + ((ub >> 16) & 1u)) & 0xffff0000u;
    return ra | rb;
}

__device__ __forceinline__ short bf1(float a) {
    unsigned ua = __float_as_uint(a);
    return (short)((ua + 0x7fffu + ((ua >> 16) & 1u)) >> 16);
}

// ---------------- hist: per-block LDS byte-histogram + per-(block,bucket) counts ----

__global__ __launch_bounds__(256) void k_hist(const int* __restrict__ dst,
                                              unsigned* __restrict__ histg,
                                              unsigned* __restrict__ bucketcnt,
                                              int E, int words, int nbkt) {
    __shared__ unsigned hist[HWORDS_MAX];  // 128 KiB
    int t = threadIdx.x;
    for (int i = t; i < words; i += 256) hist[i] = 0;
    __syncthreads();

    int chunk = (E + NBH - 1) / NBH;
    int beg = blockIdx.x * chunk;
    int end = beg + chunk; if (end > E) end = E;
    for (int i = beg + t; i < end; i += 256) {
        int d = dst[i];
        atomicAdd(&hist[d >> 2], 1u << ((d & 3) * 8));
    }
    __syncthreads();

    unsigned* outp = histg + (size_t)blockIdx.x * words;
    for (int i = t; i < words; i += 256) outp[i] = hist[i];

    // per-bucket sum of this block's counts (bucket t = words [t<<7, (t+1)<<7))
    if (t < NBKT_MAX) {
        unsigned s = 0;
        if (t < nbkt) {
            int w0 = t << (BSH - 2);
            int w1 = w0 + (1 << (BSH - 2)); if (w1 > words) w1 = words;
            for (int w = w0; w < w1; ++w) {
                unsigned v = hist[w];
                s += (v & 0xFFu) + ((v >> 8) & 0xFFu) + ((v >> 16) & 0xFFu) + ((v >> 24) & 0xFFu);
            }
        }
        bucketcnt[blockIdx.x * NBKT_MAX + t] = s;
    }
}

// ---------------- merge: cnt + dinv (validated round 13) ----------------

__global__ __launch_bounds__(256) void k_merge(const unsigned* __restrict__ histg,
                                               int words, int* __restrict__ cnt,
                                               float* __restrict__ dinv, int n) {
    int wd = blockIdx.x * 256 + threadIdx.x;
    if (wd >= words) return;
    unsigned s0 = 0, s1 = 0, s2 = 0, s3 = 0;
    const unsigned* p = histg + wd;
#pragma unroll 8
    for (int b = 0; b < NBH; ++b) {
        unsigned v = p[(size_t)b * words];
        s0 += v & 0xFFu;
        s1 += (v >> 8) & 0xFFu;
        s2 += (v >> 16) & 0xFFu;
        s3 += (v >> 24) & 0xFFu;
    }
    int nd = wd * 4;
    unsigned c[4] = {s0, s1, s2, s3};
#pragma unroll
    for (int j = 0; j < 4; ++j) {
        if (nd + j < n) {
            cnt[nd + j] = (int)c[j];
            dinv[nd + j] = rsqrtf((float)(c[j] + 1));
        }
    }
}

// ---------------- scanoff: exclusive scan of bucketcnt along blocks (per bucket) ----

__global__ __launch_bounds__(256) void k_scanoff(const unsigned* __restrict__ bucketcnt,
                                                 unsigned* __restrict__ blockoff,
                                                 unsigned* __restrict__ bucketsum) {
    __shared__ unsigned part[256];
    int k = blockIdx.x, b = threadIdx.x;
    unsigned v = bucketcnt[b * NBKT_MAX + k];
    part[b] = v;
    __syncthreads();
    for (int off = 1; off < 256; off <<= 1) {
        unsigned u = (b >= off) ? part[b - off] : 0;
        __syncthreads();
        part[b] += u;
        __syncthreads();
    }
    blockoff[b * NBKT_MAX + k] = part[b] - v;  // exclusive
    if (b == 255) bucketsum[k] = part[255];
}

// ---------------- base: exclusive scan of bucket totals ----------------

__global__ __launch_bounds__(256) void k_base(const unsigned* __restrict__ bucketsum,
                                              unsigned* __restrict__ bucketbase) {
    __shared__ unsigned part[256];
    int t = threadIdx.x;
    unsigned v = bucketsum[t];
    part[t] = v;
    __syncthreads();
    for (int off = 1; off < 256; off <<= 1) {
        unsigned u = (t >= off) ? part[t - off] : 0;
        __syncthreads();
        part[t] += u;
        __syncthreads();
    }
    bucketbase[t] = part[t] - v;
    if (t == 255) bucketbase[256] = part[255];
}

// ---------------- bfill: cursor-free counting-sort placement ----------------
// Same edge chunking as k_hist; rank within (block,bucket) via LDS counter.

__global__ __launch_bounds__(256) void k_bfill(const int* __restrict__ src,
                                               const int* __restrict__ dst,
                                               const unsigned* __restrict__ bucketbase,
                                               const unsigned* __restrict__ blockoff,
                                               unsigned* __restrict__ sorted, int E) {
    __shared__ unsigned ldc[NBKT_MAX];
    __shared__ unsigned base_l[NBKT_MAX];
    int t = threadIdx.x, b = blockIdx.x;
    ldc[t] = 0;
    base_l[t] = bucketbase[t] + blockoff[b * NBKT_MAX + t];
    __syncthreads();

    int chunk = (E + NBH - 1) / NBH;
    int beg = b * chunk;
    int end = beg + chunk; if (end > E) end = E;
    for (int i = beg + t; i < end; i += 256) {
        int d = dst[i], s = src[i];
        int k = d >> BSH;
        unsigned r = atomicAdd(&ldc[k], 1u);
        sorted[base_l[k] + r] = ((unsigned)(d & ((1 << BSH) - 1)) << 17) | (unsigned)s;
    }
}

// ---------------- layer 1 GEMM via MFMA: genc = enc4((x@W1)*dinv) -------------------

__global__ __launch_bounds__(256, 2) void k_gemm1(const float* __restrict__ x,
                                                  const float* __restrict__ W1,
                                                  const float* __restrict__ dinv,
                                                  unsigned long long* __restrict__ genc,
                                                  int n, int npanels) {
    __shared__ short xs[64 * 512];  // 64 KiB, XOR-swizzled rows

    int t = threadIdx.x;
    int lane = t & 63;
    int wv = t >> 6;
    int kg = lane >> 4;
    int lcol = lane & 15;

    bf16x8 wf[16];
#pragma unroll
    for (int s = 0; s < 16; ++s) {
#pragma unroll
        for (int j = 0; j < 8; ++j)
            wf[s][j] = bf1(W1[(s * 32 + kg * 8 + j) * FHID + lcol]);
    }

    const size_t maxoff = (size_t)n * (FIN * 4) - 16;

    for (int pb = blockIdx.x; pb < npanels; pb += gridDim.x) {
        __syncthreads();

        size_t panelbyte = (size_t)pb * 131072;
#pragma unroll 1
        for (int b = 0; b < 4; ++b) {
            float4 v[8];
#pragma unroll
            for (int i = 0; i < 8; ++i) {
                size_t off = panelbyte + (size_t)(b * 8 + i) * 4096 + (size_t)t * 16;
                if (off > maxoff) off = maxoff;
                v[i] = *reinterpret_cast<const float4*>((const char*)x + off);
            }
#pragma unroll
            for (int i = 0; i < 8; ++i) {
                int elem = (b * 8 + i) * 1024 + t * 4;
                int row = elem >> 9;
                int kc = elem & 511;
                int kcs = kc ^ ((row & 7) << 3);
                uint2 w2;
                w2.x = bfpack2(v[i].x, v[i].y);
                w2.y = bfpack2(v[i].z, v[i].w);
                *reinterpret_cast<uint2*>(&xs[row * 512 + kcs]) = w2;
            }
        }
        __syncthreads();

        int lrow = wv * 16 + lcol;
        const short* ap = &xs[lrow * 512];
        f32x4 acc = {0.0f, 0.0f, 0.0f, 0.0f};
#pragma unroll
        for (int s = 0; s < 16; ++s) {
            int kc = s * 32 + kg * 8;
            bf16x8 a = *reinterpret_cast<const bf16x8*>(ap + (kc ^ ((lrow & 7) << 3)));
            acc = __builtin_amdgcn_mfma_f32_16x16x32_bf16(a, wf[s], acc, 0, 0, 0);
        }

        int panelrow = pb * 64 + wv * 16;
#pragma unroll
        for (int r = 0; r < 4; ++r) {
            int grow = panelrow + kg * 4 + r;
            float dv = (grow < n) ? dinv[grow] : 0.0f;
            float val = acc[r] * dv;
            float v1 = __shfl_xor(val, 1);
            float v2 = __shfl_xor(val, 2);
            float v3 = __shfl_xor(val, 3);
            if (grow < n && (lcol & 3) == 0)
                genc[(size_t)grow * 4 + (lcol >> 2)] = enc4(val, v1, v2, v3);
        }
    }
}

// ---------------- bucket aggregate: gather + LDS u64 adds, zero global atomics ------
// Block k owns nodes [k<<9, (k+1)<<9). Init acc with own gin rows (self-loop),
// accumulate gathered rows via LDS atomics (exact integer sums), flush plain stores.

__global__ __launch_bounds__(256) void k_bagg(const unsigned* __restrict__ sorted,
                                              const unsigned* __restrict__ bucketbase,
                                              const unsigned long long* __restrict__ gin,
                                              unsigned long long* __restrict__ gout,
                                              int n) {
    __shared__ unsigned long long acc[512 * 4];  // 16 KiB
    int k = blockIdx.x, t = threadIdx.x;
    int node0 = k << BSH;
    int nlocal = n - node0; if (nlocal > 512) nlocal = 512;
    int lim = nlocal * 4;

    for (int i = t; i < 512 * 4; i += 256)
        acc[i] = (i < lim) ? gin[(size_t)node0 * 4 + i] : 0ULL;  // self-loop init
    __syncthreads();

    int beg = (int)bucketbase[k], end = (int)bucketbase[k + 1];
    for (int i = beg + t; i < end; i += 256) {
        unsigned pr = sorted[i];
        int s = (int)(pr & 0x1FFFFu);
        int dl = (int)(pr >> 17);
        const ulonglong2* gp = reinterpret_cast<const ulonglong2*>(gin + (size_t)s * 4);
        ulonglong2 a = gp[0];
        ulonglong2 b = gp[1];
        unsigned long long* ap = &acc[dl * 4];
        atomicAdd(&ap[0], a.x);
        atomicAdd(&ap[1], a.y);
        atomicAdd(&ap[2], b.x);
        atomicAdd(&ap[3], b.y);
    }
    __syncthreads();

    for (int i = t; i < lim; i += 256)
        gout[(size_t)node0 * 4 + i] = acc[i];
}

// ---------------- finish layer 1: decode; p = relu(s*dinv + b1)*dinv; re-encode -----

__global__ void k_finish1(const unsigned long long* __restrict__ agg,
                          const int* __restrict__ cnt,
                          const float* __restrict__ dinv,
                          const float* __restrict__ b1,
                          unsigned long long* __restrict__ penc, int n) {
    int nd = blockIdx.x * blockDim.x + threadIdx.x;
    if (nd >= n) return;
    float dv = dinv[nd];
    float cb = (float)(cnt[nd] + 1) * ENC_B;
    const unsigned long long* ar = agg + (size_t)nd * 4;
    unsigned long long* pp = penc + (size_t)nd * 4;
#pragma unroll
    for (int j = 0; j < 4; ++j) {
        unsigned long long w = ar[j];
        float s0 = (float)(unsigned)(w & 0xFFFF) * ENC_SI - cb;
        float s1 = (float)(unsigned)((w >> 16) & 0xFFFF) * ENC_SI - cb;
        float s2 = (float)(unsigned)((w >> 32) & 0xFFFF) * ENC_SI - cb;
        float s3 = (float)(unsigned)((w >> 48) & 0xFFFF) * ENC_SI - cb;
        float r0 = fmaxf(fmaf(s0, dv, b1[4 * j + 0]), 0.0f) * dv;
        float r1 = fmaxf(fmaf(s1, dv, b1[4 * j + 1]), 0.0f) * dv;
        float r2 = fmaxf(fmaf(s2, dv, b1[4 * j + 2]), 0.0f) * dv;
        float r3 = fmaxf(fmaf(s3, dv, b1[4 * j + 3]), 0.0f) * dv;
        pp[j] = enc4(r0, r1, r2, r3);
    }
}

// ---------------- finish layer 2: decode; out = log_softmax((s*dinv) @ W2 + b2) -----

__global__ __launch_bounds__(256) void k_finish2(const unsigned long long* __restrict__ aggp,
                                                 const int* __restrict__ cnt,
                                                 const float* __restrict__ dinv,
                                                 const float* __restrict__ W2,
                                                 const float* __restrict__ b2,
                                                 float* __restrict__ out, int n) {
    __shared__ float Wl[FHID * FOUT];
    __shared__ float bl[FOUT];
    for (int i = threadIdx.x; i < FHID * FOUT; i += 256) Wl[i] = W2[i];
    if (threadIdx.x < FOUT) bl[threadIdx.x] = b2[threadIdx.x];
    __syncthreads();

    int nd = blockIdx.x * 256 + threadIdx.x;
    if (nd >= n) return;

    float dv = dinv[nd];
    float cb = (float)(cnt[nd] + 1) * ENC_B;
    float q[FHID];
    const unsigned long long* ap = aggp + (size_t)nd * 4;
#pragma unroll
    for (int j = 0; j < 4; ++j) {
        unsigned long long w = ap[j];
        q[4 * j + 0] = ((float)(unsigned)(w & 0xFFFF) * ENC_SI - cb) * dv;
        q[4 * j + 1] = ((float)(unsigned)((w >> 16) & 0xFFFF) * ENC_SI - cb) * dv;
        q[4 * j + 2] = ((float)(unsigned)((w >> 32) & 0xFFFF) * ENC_SI - cb) * dv;
        q[4 * j + 3] = ((float)(unsigned)((w >> 48) & 0xFFFF) * ENC_SI - cb) * dv;
    }

    float acc[FOUT];
#pragma unroll
    for (int o = 0; o < FOUT; ++o) acc[o] = bl[o];
#pragma unroll
    for (int kk = 0; kk < FHID; ++kk) {
        float qs = q[kk];
        const float* wrow = &Wl[kk * FOUT];
#pragma unroll
        for (int o = 0; o < FOUT; ++o) acc[o] = fmaf(qs, wrow[o], acc[o]);
    }

    float m = acc[0];
#pragma unroll
    for (int o = 1; o < FOUT; ++o) m = fmaxf(m, acc[o]);
    float ssum = 0.0f;
#pragma unroll
    for (int o = 0; o < FOUT; ++o) ssum += expf(acc[o] - m);
    float lse = m + logf(ssum);

    float4* op = reinterpret_cast<float4*>(out + (size_t)nd * FOUT);
#pragma unroll
    for (int tt = 0; tt < FOUT / 4; ++tt) {
        float4 v;
        v.x = acc[4 * tt + 0] - lse;
        v.y = acc[4 * tt + 1] - lse;
        v.z = acc[4 * tt + 2] - lse;
        v.w = acc[4 * tt + 3] - lse;
        op[tt] = v;
    }
}

// ---------------- launch ----------------

extern "C" void kernel_launch(void* const* d_in, const int* in_sizes, int n_in,
                              void* d_out, int out_size, void* d_ws, size_t ws_size,
                              hipStream_t stream) {
    const float* x  = (const float*)d_in[0];
    const int*   ei = (const int*)d_in[1];
    const float* W1 = (const float*)d_in[2];
    const float* b1 = (const float*)d_in[3];
    const float* W2 = (const float*)d_in[4];
    const float* b2 = (const float*)d_in[5];

    const int fh = in_sizes[3];              // 16
    const int fi = in_sizes[2] / fh;         // 512
    const int n  = in_sizes[0] / fi;         // 100000
    const int E  = in_sizes[1] / 2;          // 3200000
    (void)n_in; (void)out_size; (void)ws_size;

    const int* src = ei;
    const int* dst = ei + E;

    const int words = (n + 3) >> 2;
    const int nbkt = (n + (1 << BSH) - 1) >> BSH;   // 196

    char* w = (char*)d_ws;
    unsigned* histg     = (unsigned*)w;                 w += (size_t)NBH * words * 4;
    unsigned* bucketcnt = (unsigned*)w;                 w += (size_t)NBH * NBKT_MAX * 4;
    unsigned* blockoff  = (unsigned*)w;                 w += (size_t)NBH * NBKT_MAX * 4;
    unsigned* bucketsum = (unsigned*)w;                 w += (size_t)NBKT_MAX * 4;
    unsigned* bucketbase= (unsigned*)w;                 w += (size_t)(NBKT_MAX + 8) * 4;
    int*   cnt  = (int*)w;                              w += (size_t)n * 4;
    float* dinv = (float*)w;                            w += (size_t)n * 4;
    unsigned long long* genc = (unsigned long long*)w;  w += (size_t)n * 4 * 8;
    unsigned long long* agg  = (unsigned long long*)w;  w += (size_t)n * 4 * 8;
    unsigned long long* penc = (unsigned long long*)w;  w += (size_t)n * 4 * 8;
    unsigned long long* aggp = (unsigned long long*)w;  w += (size_t)n * 4 * 8;
    unsigned* sorted = (unsigned*)w;                    /* E * 4 bytes */

    float* out = (float*)d_out;

    const int TB = 256;
    const int nb_n = (n + TB - 1) / TB;
    const int npanels = (n + 63) / 64;

    k_hist<<<NBH, TB, 0, stream>>>(dst, histg, bucketcnt, E, words, nbkt);
    k_merge<<<(words + TB - 1) / TB, TB, 0, stream>>>(histg, words, cnt, dinv, n);
    k_scanoff<<<NBKT_MAX, TB, 0, stream>>>(bucketcnt, blockoff, bucketsum);
    k_base<<<1, TB, 0, stream>>>(bucketsum, bucketbase);
    k_bfill<<<NBH, TB, 0, stream>>>(src, dst, bucketbase, blockoff, sorted, E);

    k_gemm1<<<512, TB, 0, stream>>>(x, W1, dinv, genc, n, npanels);

    k_bagg<<<nbkt, TB, 0, stream>>>(sorted, bucketbase, genc, agg, n);
    k_finish1<<<nb_n, TB, 0, stream>>>(agg, cnt, dinv, b1, penc, n);
    k_bagg<<<nbkt, TB, 0, stream>>>(sorted, bucketbase, penc, aggp, n);
    k_finish2<<<nb_n, TB, 0, stream>>>(aggp, cnt, dinv, W2, b2, out, n);
}

// Round 17
// 203.805 us; speedup vs baseline: 5.9795x; 1.0575x over previous
//
#include <hip/hip_runtime.h>

#define FIN 512
#define FHID 16
#define FOUT 40
#define NBH 256           // hist/fill blocks (edge chunking)
#define HWORDS_MAX 32768  // LDS byte-hist words -> n <= 131072
#define BSH 7             // bucket = node >> 7 (128 nodes/bucket)
#define NPB 128           // nodes per bucket
#define NBKT_MAX 1024

typedef __attribute__((ext_vector_type(8))) short bf16x8;
typedef __attribute__((ext_vector_type(4))) float f32x4;

// 4x16-bit biased fixed-point fields per u64 (validated r10/12/13/15/16).
// Integer sums are exact & commutative -> bit-deterministic in any order.
#define ENC_S 32.0f
#define ENC_SI 0.03125f
#define ENC_B 8.0f

__device__ __forceinline__ unsigned long long enc4(float a, float b, float c, float d) {
    unsigned r0 = (unsigned)fmaf(a, ENC_S, 256.5f);
    unsigned r1 = (unsigned)fmaf(b, ENC_S, 256.5f);
    unsigned r2 = (unsigned)fmaf(c, ENC_S, 256.5f);
    unsigned r3 = (unsigned)fmaf(d, ENC_S, 256.5f);
    return (unsigned long long)r0 | ((unsigned long long)r1 << 16) |
           ((unsigned long long)r2 << 32) | ((unsigned long long)r3 << 48);
}

__device__ __forceinline__ unsigned bfpack2(float a, float b) {
    unsigned ua = __float_as_uint(a);
    unsigned ub = __float_as_uint(b);
    unsigned ra = (ua + 0x7fffu + ((ua >> 16) & 1u)) >> 16;
    unsigned rb = (ub + 0x7fffu + ((ub >> 16) & 1u)) & 0xffff0000u;
    return ra | rb;
}

__device__ __forceinline__ short bf1(float a) {
    unsigned ua = __float_as_uint(a);
    return (short)((ua + 0x7fffu + ((ua >> 16) & 1u)) >> 16);
}

// ---------------- hist: LDS byte-histogram + per-(block,bucket) counts --------------

__global__ __launch_bounds__(256) void k_hist(const int* __restrict__ dst,
                                              unsigned* __restrict__ histg,
                                              unsigned* __restrict__ bucketcnt,
                                              int E, int words, int nbkt) {
    __shared__ unsigned hist[HWORDS_MAX];
    int t = threadIdx.x;
    for (int i = t; i < words; i += 256) hist[i] = 0;
    __syncthreads();

    int chunk = (E + NBH - 1) / NBH;
    int beg = blockIdx.x * chunk;
    int end = beg + chunk; if (end > E) end = E;
    for (int i = beg + t; i < end; i += 256) {
        int d = dst[i];
        atomicAdd(&hist[d >> 2], 1u << ((d & 3) * 8));
    }
    __syncthreads();

    unsigned* outp = histg + (size_t)blockIdx.x * words;
    for (int i = t; i < words; i += 256) outp[i] = hist[i];

    // per-bucket sums: bucket k covers words [k<<5, (k+1)<<5)
    for (int k = t; k < NBKT_MAX; k += 256) {
        unsigned s = 0;
        if (k < nbkt) {
            int w0 = k << (BSH - 2);
            int w1 = w0 + (1 << (BSH - 2)); if (w1 > words) w1 = words;
            for (int w = w0; w < w1; ++w) {
                unsigned v = hist[w];
                s += (v & 0xFFu) + ((v >> 8) & 0xFFu) + ((v >> 16) & 0xFFu) + ((v >> 24) & 0xFFu);
            }
        }
        bucketcnt[blockIdx.x * NBKT_MAX + k] = s;
    }
}

// ---------------- merge: cnt + dinv ----------------

__global__ __launch_bounds__(256) void k_merge(const unsigned* __restrict__ histg,
                                               int words, int* __restrict__ cnt,
                                               float* __restrict__ dinv, int n) {
    int wd = blockIdx.x * 256 + threadIdx.x;
    if (wd >= words) return;
    unsigned s0 = 0, s1 = 0, s2 = 0, s3 = 0;
    const unsigned* p = histg + wd;
#pragma unroll 8
    for (int b = 0; b < NBH; ++b) {
        unsigned v = p[(size_t)b * words];
        s0 += v & 0xFFu;
        s1 += (v >> 8) & 0xFFu;
        s2 += (v >> 16) & 0xFFu;
        s3 += (v >> 24) & 0xFFu;
    }
    int nd = wd * 4;
    unsigned c[4] = {s0, s1, s2, s3};
#pragma unroll
    for (int j = 0; j < 4; ++j) {
        if (nd + j < n) {
            cnt[nd + j] = (int)c[j];
            dinv[nd + j] = rsqrtf((float)(c[j] + 1));
        }
    }
}

// ---------------- scanoff: per-bucket exclusive scan across the 256 fill blocks -----

__global__ __launch_bounds__(256) void k_scanoff(const unsigned* __restrict__ bucketcnt,
                                                 unsigned* __restrict__ blockoff,
                                                 unsigned* __restrict__ bucketsum) {
    __shared__ unsigned part[256];
    int k = blockIdx.x, b = threadIdx.x;
    unsigned v = bucketcnt[b * NBKT_MAX + k];
    part[b] = v;
    __syncthreads();
    for (int off = 1; off < 256; off <<= 1) {
        unsigned u = (b >= off) ? part[b - off] : 0;
        __syncthreads();
        part[b] += u;
        __syncthreads();
    }
    blockoff[b * NBKT_MAX + k] = part[b] - v;
    if (b == 255) bucketsum[k] = part[255];
}

// ---------------- base: exclusive scan of 1024 bucket totals (int4, one block) ------

__global__ __launch_bounds__(256) void k_base(const unsigned* __restrict__ bucketsum,
                                              unsigned* __restrict__ bucketbase) {
    __shared__ unsigned part[256];
    int t = threadIdx.x;
    uint4 c4 = reinterpret_cast<const uint4*>(bucketsum)[t];
    unsigned s = c4.x + c4.y + c4.z + c4.w;
    part[t] = s;
    __syncthreads();
    for (int off = 1; off < 256; off <<= 1) {
        unsigned u = (t >= off) ? part[t - off] : 0;
        __syncthreads();
        part[t] += u;
        __syncthreads();
    }
    unsigned base = t ? part[t - 1] : 0;
    uint4 o;
    o.x = base;
    o.y = o.x + c4.x;
    o.z = o.y + c4.y;
    o.w = o.z + c4.z;
    reinterpret_cast<uint4*>(bucketbase)[t] = o;
    if (t == 255) bucketbase[NBKT_MAX] = part[255];
}

// ---------------- bfill: cursor-free counting-sort placement ----------------

__global__ __launch_bounds__(256) void k_bfill(const int* __restrict__ src,
                                               const int* __restrict__ dst,
                                               const unsigned* __restrict__ bucketbase,
                                               const unsigned* __restrict__ blockoff,
                                               unsigned* __restrict__ sorted, int E) {
    __shared__ unsigned ldc[NBKT_MAX];     // 4 KiB
    __shared__ unsigned base_l[NBKT_MAX];  // 4 KiB
    int t = threadIdx.x, b = blockIdx.x;
    for (int k = t; k < NBKT_MAX; k += 256) {
        ldc[k] = 0;
        base_l[k] = bucketbase[k] + blockoff[b * NBKT_MAX + k];
    }
    __syncthreads();

    int chunk = (E + NBH - 1) / NBH;
    int beg = b * chunk;
    int end = beg + chunk; if (end > E) end = E;
    for (int i = beg + t; i < end; i += 256) {
        int d = dst[i], s = src[i];
        int k = d >> BSH;
        unsigned r = atomicAdd(&ldc[k], 1u);
        sorted[base_l[k] + r] = ((unsigned)(d & (NPB - 1)) << 17) | (unsigned)s;
    }
}

// ---------------- layer 1 GEMM via MFMA: genc = enc4((x@W1)*dinv) -------------------

__global__ __launch_bounds__(256, 2) void k_gemm1(const float* __restrict__ x,
                                                  const float* __restrict__ W1,
                                                  const float* __restrict__ dinv,
                                                  unsigned long long* __restrict__ genc,
                                                  int n, int npanels) {
    __shared__ short xs[64 * 512];  // 64 KiB, XOR-swizzled rows

    int t = threadIdx.x;
    int lane = t & 63;
    int wv = t >> 6;
    int kg = lane >> 4;
    int lcol = lane & 15;

    bf16x8 wf[16];
#pragma unroll
    for (int s = 0; s < 16; ++s) {
#pragma unroll
        for (int j = 0; j < 8; ++j)
            wf[s][j] = bf1(W1[(s * 32 + kg * 8 + j) * FHID + lcol]);
    }

    const size_t maxoff = (size_t)n * (FIN * 4) - 16;

    for (int pb = blockIdx.x; pb < npanels; pb += gridDim.x) {
        __syncthreads();

        size_t panelbyte = (size_t)pb * 131072;
#pragma unroll 1
        for (int b = 0; b < 4; ++b) {
            float4 v[8];
#pragma unroll
            for (int i = 0; i < 8; ++i) {
                size_t off = panelbyte + (size_t)(b * 8 + i) * 4096 + (size_t)t * 16;
                if (off > maxoff) off = maxoff;
                v[i] = *reinterpret_cast<const float4*>((const char*)x + off);
            }
#pragma unroll
            for (int i = 0; i < 8; ++i) {
                int elem = (b * 8 + i) * 1024 + t * 4;
                int row = elem >> 9;
                int kc = elem & 511;
                int kcs = kc ^ ((row & 7) << 3);
                uint2 w2;
                w2.x = bfpack2(v[i].x, v[i].y);
                w2.y = bfpack2(v[i].z, v[i].w);
                *reinterpret_cast<uint2*>(&xs[row * 512 + kcs]) = w2;
            }
        }
        __syncthreads();

        int lrow = wv * 16 + lcol;
        const short* ap = &xs[lrow * 512];
        f32x4 acc = {0.0f, 0.0f, 0.0f, 0.0f};
#pragma unroll
        for (int s = 0; s < 16; ++s) {
            int kc = s * 32 + kg * 8;
            bf16x8 a = *reinterpret_cast<const bf16x8*>(ap + (kc ^ ((lrow & 7) << 3)));
            acc = __builtin_amdgcn_mfma_f32_16x16x32_bf16(a, wf[s], acc, 0, 0, 0);
        }

        int panelrow = pb * 64 + wv * 16;
#pragma unroll
        for (int r = 0; r < 4; ++r) {
            int grow = panelrow + kg * 4 + r;
            float dv = (grow < n) ? dinv[grow] : 0.0f;
            float val = acc[r] * dv;
            float v1 = __shfl_xor(val, 1);
            float v2 = __shfl_xor(val, 2);
            float v3 = __shfl_xor(val, 3);
            if (grow < n && (lcol & 3) == 0)
                genc[(size_t)grow * 4 + (lcol >> 2)] = enc4(val, v1, v2, v3);
        }
    }
}

// ---------------- bucket aggregate + FUSED epilogue ----------------
// Block k owns nodes [k*128, k*128+128). LDS acc (4KB) init w/ self-loop rows;
// 4-deep batched gather (r3/4 lesson: compiler won't pipeline sorted->gather);
// LAYER 1 epilogue: decode+relu+re-encode -> penc. LAYER 2: W2 matvec+log_softmax -> out.

template <int LAYER>
__global__ __launch_bounds__(256) void k_bagg(const unsigned* __restrict__ sorted,
                                              const unsigned* __restrict__ bucketbase,
                                              const unsigned long long* __restrict__ gin,
                                              const float* __restrict__ dinv,
                                              const int* __restrict__ cnt,
                                              const float* __restrict__ b1,
                                              const float* __restrict__ W2,
                                              const float* __restrict__ b2,
                                              unsigned long long* __restrict__ penc,
                                              float* __restrict__ out, int n) {
    __shared__ unsigned long long acc[NPB * 4];  // 4 KiB
    __shared__ float Wl[FHID * FOUT];
    __shared__ float bl[FOUT];

    int k = blockIdx.x, t = threadIdx.x;
    int node0 = k << BSH;
    int nlocal = n - node0; if (nlocal > NPB) nlocal = NPB;
    int lim = nlocal * 4;

    for (int i = t; i < NPB * 4; i += 256)
        acc[i] = (i < lim) ? gin[(size_t)node0 * 4 + i] : 0ULL;  // self-loop init
    if (LAYER == 2) {
        for (int i = t; i < FHID * FOUT; i += 256) Wl[i] = W2[i];
        if (t < FOUT) bl[t] = b2[t];
    }
    __syncthreads();

    int beg = (int)bucketbase[k], end = (int)bucketbase[k + 1];
    int i = beg + t;
    for (; i + 256 * 3 < end; i += 256 * 4) {
        unsigned pr[4];
#pragma unroll
        for (int j = 0; j < 4; ++j) pr[j] = sorted[i + 256 * j];
        ulonglong2 a[4], b[4];
#pragma unroll
        for (int j = 0; j < 4; ++j) {
            const ulonglong2* gp =
                reinterpret_cast<const ulonglong2*>(gin + (size_t)(pr[j] & 0x1FFFFu) * 4);
            a[j] = gp[0];
            b[j] = gp[1];
        }
#pragma unroll
        for (int j = 0; j < 4; ++j) {
            unsigned long long* ap = &acc[(pr[j] >> 17) * 4];
            atomicAdd(&ap[0], a[j].x);
            atomicAdd(&ap[1], a[j].y);
            atomicAdd(&ap[2], b[j].x);
            atomicAdd(&ap[3], b[j].y);
        }
    }
    for (; i < end; i += 256) {
        unsigned pr = sorted[i];
        const ulonglong2* gp =
            reinterpret_cast<const ulonglong2*>(gin + (size_t)(pr & 0x1FFFFu) * 4);
        ulonglong2 a = gp[0], b = gp[1];
        unsigned long long* ap = &acc[(pr >> 17) * 4];
        atomicAdd(&ap[0], a.x);
        atomicAdd(&ap[1], a.y);
        atomicAdd(&ap[2], b.x);
        atomicAdd(&ap[3], b.y);
    }
    __syncthreads();

    if (LAYER == 1) {
        for (int i2 = t; i2 < lim; i2 += 256) {
            int nd = node0 + (i2 >> 2);
            int j = i2 & 3;
            float dv = dinv[nd];
            float cb = (float)(cnt[nd] + 1) * ENC_B;
            unsigned long long w = acc[i2];
            float s0 = (float)(unsigned)(w & 0xFFFF) * ENC_SI - cb;
            float s1 = (float)(unsigned)((w >> 16) & 0xFFFF) * ENC_SI - cb;
            float s2 = (float)(unsigned)((w >> 32) & 0xFFFF) * ENC_SI - cb;
            float s3 = (float)(unsigned)((w >> 48) & 0xFFFF) * ENC_SI - cb;
            float r0 = fmaxf(fmaf(s0, dv, b1[4 * j + 0]), 0.0f) * dv;
            float r1 = fmaxf(fmaf(s1, dv, b1[4 * j + 1]), 0.0f) * dv;
            float r2 = fmaxf(fmaf(s2, dv, b1[4 * j + 2]), 0.0f) * dv;
            float r3 = fmaxf(fmaf(s3, dv, b1[4 * j + 3]), 0.0f) * dv;
            penc[(size_t)node0 * 4 + i2] = enc4(r0, r1, r2, r3);
        }
    } else {
        if (t < nlocal) {
            int nd = node0 + t;
            float dv = dinv[nd];
            float cb = (float)(cnt[nd] + 1) * ENC_B;
            float q[FHID];
#pragma unroll
            for (int j = 0; j < 4; ++j) {
                unsigned long long w = acc[t * 4 + j];
                q[4 * j + 0] = ((float)(unsigned)(w & 0xFFFF) * ENC_SI - cb) * dv;
                q[4 * j + 1] = ((float)(unsigned)((w >> 16) & 0xFFFF) * ENC_SI - cb) * dv;
                q[4 * j + 2] = ((float)(unsigned)((w >> 32) & 0xFFFF) * ENC_SI - cb) * dv;
                q[4 * j + 3] = ((float)(unsigned)((w >> 48) & 0xFFFF) * ENC_SI - cb) * dv;
            }
            float av[FOUT];
#pragma unroll
            for (int o = 0; o < FOUT; ++o) av[o] = bl[o];
#pragma unroll
            for (int kk = 0; kk < FHID; ++kk) {
                float qs = q[kk];
                const float* wrow = &Wl[kk * FOUT];
#pragma unroll
                for (int o = 0; o < FOUT; ++o) av[o] = fmaf(qs, wrow[o], av[o]);
            }
            float m = av[0];
#pragma unroll
            for (int o = 1; o < FOUT; ++o) m = fmaxf(m, av[o]);
            float ssum = 0.0f;
#pragma unroll
            for (int o = 0; o < FOUT; ++o) ssum += expf(av[o] - m);
            float lse = m + logf(ssum);
            float4* op = reinterpret_cast<float4*>(out + (size_t)nd * FOUT);
#pragma unroll
            for (int tt = 0; tt < FOUT / 4; ++tt) {
                float4 v;
                v.x = av[4 * tt + 0] - lse;
                v.y = av[4 * tt + 1] - lse;
                v.z = av[4 * tt + 2] - lse;
                v.w = av[4 * tt + 3] - lse;
                op[tt] = v;
            }
        }
    }
}

// ---------------- launch ----------------

extern "C" void kernel_launch(void* const* d_in, const int* in_sizes, int n_in,
                              void* d_out, int out_size, void* d_ws, size_t ws_size,
                              hipStream_t stream) {
    const float* x  = (const float*)d_in[0];
    const int*   ei = (const int*)d_in[1];
    const float* W1 = (const float*)d_in[2];
    const float* b1 = (const float*)d_in[3];
    const float* W2 = (const float*)d_in[4];
    const float* b2 = (const float*)d_in[5];

    const int fh = in_sizes[3];              // 16
    const int fi = in_sizes[2] / fh;         // 512
    const int n  = in_sizes[0] / fi;         // 100000
    const int E  = in_sizes[1] / 2;          // 3200000
    (void)n_in; (void)out_size; (void)ws_size;

    const int* src = ei;
    const int* dst = ei + E;

    const int words = (n + 3) >> 2;
    const int nbkt = (n + NPB - 1) >> BSH;   // 782

    char* w = (char*)d_ws;
    unsigned* histg     = (unsigned*)w;                 w += (size_t)NBH * words * 4;
    unsigned* bucketcnt = (unsigned*)w;                 w += (size_t)NBH * NBKT_MAX * 4;
    unsigned* blockoff  = (unsigned*)w;                 w += (size_t)NBH * NBKT_MAX * 4;
    unsigned* bucketsum = (unsigned*)w;                 w += (size_t)NBKT_MAX * 4;
    unsigned* bucketbase= (unsigned*)w;                 w += (size_t)(NBKT_MAX + 8) * 4;
    int*   cnt  = (int*)w;                              w += (size_t)n * 4;
    float* dinv = (float*)w;                            w += (size_t)n * 4;
    unsigned long long* genc = (unsigned long long*)w;  w += (size_t)n * 4 * 8;
    unsigned long long* penc = (unsigned long long*)w;  w += (size_t)n * 4 * 8;
    unsigned* sorted = (unsigned*)w;                    /* E * 4 bytes */

    float* out = (float*)d_out;

    const int TB = 256;
    const int npanels = (n + 63) / 64;

    k_hist<<<NBH, TB, 0, stream>>>(dst, histg, bucketcnt, E, words, nbkt);
    k_merge<<<(words + TB - 1) / TB, TB, 0, stream>>>(histg, words, cnt, dinv, n);
    k_scanoff<<<NBKT_MAX, TB, 0, stream>>>(bucketcnt, blockoff, bucketsum);
    k_base<<<1, TB, 0, stream>>>(bucketsum, bucketbase);
    k_bfill<<<NBH, TB, 0, stream>>>(src, dst, bucketbase, blockoff, sorted, E);

    k_gemm1<<<512, TB, 0, stream>>>(x, W1, dinv, genc, n, npanels);

    k_bagg<1><<<nbkt, TB, 0, stream>>>(sorted, bucketbase, genc, dinv, cnt, b1, W2, b2,
                                       penc, out, n);
    k_bagg<2><<<nbkt, TB, 0, stream>>>(sorted, bucketbase, penc, dinv, cnt, b1, W2, b2,
                                       genc, out, n);
}